// Round 3
// baseline (436.554 us; speedup 1.0000x reference)
//
#include <hip/hip_runtime.h>

// ---------------------------------------------------------------------------
// VelocityEncoder fully-fused pipeline for MI355X (gfx950)  — round 3
//   Changes vs round 2:
//   * 32-row blocks / 256 threads / 32 KiB LDS, __launch_bounds__(256,4)
//     -> VGPR cap 128 (was squeezed to 64), 4 blocks/CU
//   * branchless sort4 + bitonic-lower-half merge for exact top-4
//     (u64 keys = valbits<<32 | idx; unique keys -> exact jax top_k ties)
// ---------------------------------------------------------------------------

typedef __bf16 bf16x8 __attribute__((ext_vector_type(8)));
typedef unsigned short u16x8 __attribute__((ext_vector_type(8)));
typedef float f32x16 __attribute__((ext_vector_type(16)));

static __device__ __forceinline__ unsigned short f2bf(float x) {
    unsigned u = __float_as_uint(x);
    u += 0x7FFFu + ((u >> 16) & 1u);   // round-to-nearest-even
    return (unsigned short)(u >> 16);
}
static __device__ __forceinline__ float bf2f(unsigned short u) {
    return __uint_as_float(((unsigned)u) << 16);
}

#define UMIN64(a, b) ((a) < (b) ? (a) : (b))
#define CE64(x, y)                                                         \
    do {                                                                   \
        unsigned long long _mn = (x) < (y) ? (x) : (y);                    \
        unsigned long long _mx = (x) < (y) ? (y) : (x);                    \
        (x) = _mn; (y) = _mx;                                              \
    } while (0)

#define KEY(val, idx)                                                      \
    ((((unsigned long long)__float_as_uint(val)) << 32) | (unsigned)(idx))

// ---------------------------------------------------------------------------
// W2 split: fp32 [k][n] -> bf16 hi/lo, layout [kt=k>>5][n][k&31]
// ---------------------------------------------------------------------------
__global__ __launch_bounds__(256) void w2split_kernel(
    const float* __restrict__ W2,
    unsigned short* __restrict__ bt_hi, unsigned short* __restrict__ bt_lo)
{
    const int k = blockIdx.x;    // 0..255
    const int n = threadIdx.x;   // 0..255
    const float w = W2[k * 256 + n];
    const unsigned short hi = f2bf(w);
    const unsigned short lo = f2bf(w - bf2f(hi));
    const size_t off = (size_t)(k >> 5) * 8192 + (size_t)n * 32 + (k & 31);
    bt_hi[off] = hi;
    bt_lo[off] = lo;
}

// ---------------------------------------------------------------------------
// LDS A-tile layout (ushort units), total 16384 ushorts = 32 KiB:
//   addr = kt*2048 + plane*1024 + (row>>1)*64 + phys*8 + elem
//   phys = (((row&1)<<2) | q) ^ ((row>>1)&7),  q = (k&31)>>3, elem = k&7
// ---------------------------------------------------------------------------

static __device__ __forceinline__ void process_row(
    float4 c0, float4 c1, float4 c2, float4 c3,
    int r, int lr, int lane,
    const float* __restrict__ vel,
    const float4 w1r0, const float4 w1r1, const float4 w1r2,
    const float4 w1r3, const float4 w1r4, const float4 w1r5,
    const float4 bb, const float4 g, const float4 be,
    unsigned short* __restrict__ A_lds)
{
    const int ib = lane * 4;

    // group 0 -> running top-4 (sorted ascending u64 keys)
    unsigned long long r0, r1, r2, r3;
    {
        r0 = KEY(c0.x, ib + 0);   r1 = KEY(c0.y, ib + 1);
        r2 = KEY(c0.z, ib + 2);   r3 = KEY(c0.w, ib + 3);
        CE64(r0, r2); CE64(r1, r3); CE64(r0, r1); CE64(r2, r3); CE64(r1, r2);
    }
    // groups 1..3: sort4 then bitonic lower-half merge into running
    #pragma unroll
    for (int j = 1; j < 4; ++j) {
        const float4 cj = (j == 1) ? c1 : (j == 2) ? c2 : c3;
        const int gb = j * 256 + ib;
        unsigned long long g0 = KEY(cj.x, gb + 0), g1 = KEY(cj.y, gb + 1);
        unsigned long long g2 = KEY(cj.z, gb + 2), g3 = KEY(cj.w, gb + 3);
        CE64(g0, g2); CE64(g1, g3); CE64(g0, g1); CE64(g2, g3); CE64(g1, g2);
        unsigned long long l0 = UMIN64(r0, g3);
        unsigned long long l1 = UMIN64(r1, g2);
        unsigned long long l2 = UMIN64(r2, g1);
        unsigned long long l3 = UMIN64(r3, g0);
        CE64(l0, l2); CE64(l1, l3); CE64(l0, l1); CE64(l2, l3);
        r0 = l0; r1 = l1; r2 = l2; r3 = l3;
    }

    // 6-level bitonic top-4 allreduce across 64 lanes
    #pragma unroll
    for (int s = 1; s < 64; s <<= 1) {
        unsigned long long p0 = __shfl_xor(r0, s);
        unsigned long long p1 = __shfl_xor(r1, s);
        unsigned long long p2 = __shfl_xor(r2, s);
        unsigned long long p3 = __shfl_xor(r3, s);
        unsigned long long l0 = UMIN64(r0, p3);
        unsigned long long l1 = UMIN64(r1, p2);
        unsigned long long l2 = UMIN64(r2, p1);
        unsigned long long l3 = UMIN64(r3, p0);
        CE64(l0, l2); CE64(l1, l3); CE64(l0, l1); CE64(l2, l3);
        r0 = l0; r1 = l1; r2 = l2; r3 = l3;
    }
    // neighbors = 2nd..4th smallest (reference drops idx[...,0])
    const unsigned i1 = (unsigned)r1, i2 = (unsigned)r2, i3 = (unsigned)r3;

    const float* va = vel + (size_t)r * 3;
    const size_t vb = (size_t)((r >> 10) << 10) * 3;
    const float* n1 = vel + vb + (size_t)i1 * 3;
    const float* n2 = vel + vb + (size_t)i2 * 3;
    const float* n3 = vel + vb + (size_t)i3 * 3;
    const float ax = va[0], ay = va[1], az = va[2];
    const float mx = (n1[0] + n2[0] + n3[0]) * (1.0f / 3.0f);
    const float my = (n1[1] + n2[1] + n3[1]) * (1.0f / 3.0f);
    const float mz = (n1[2] + n2[2] + n3[2]) * (1.0f / 3.0f);
    const float cb[6] = {ax, ay, az, ax - mx, ay - my, az - mz};

    // h[e] for e = lane*4 .. lane*4+3
    float h0 = bb.x, h1 = bb.y, h2 = bb.z, h3 = bb.w;
    h0 = fmaf(cb[0], w1r0.x, h0); h1 = fmaf(cb[0], w1r0.y, h1);
    h2 = fmaf(cb[0], w1r0.z, h2); h3 = fmaf(cb[0], w1r0.w, h3);
    h0 = fmaf(cb[1], w1r1.x, h0); h1 = fmaf(cb[1], w1r1.y, h1);
    h2 = fmaf(cb[1], w1r1.z, h2); h3 = fmaf(cb[1], w1r1.w, h3);
    h0 = fmaf(cb[2], w1r2.x, h0); h1 = fmaf(cb[2], w1r2.y, h1);
    h2 = fmaf(cb[2], w1r2.z, h2); h3 = fmaf(cb[2], w1r2.w, h3);
    h0 = fmaf(cb[3], w1r3.x, h0); h1 = fmaf(cb[3], w1r3.y, h1);
    h2 = fmaf(cb[3], w1r3.z, h2); h3 = fmaf(cb[3], w1r3.w, h3);
    h0 = fmaf(cb[4], w1r4.x, h0); h1 = fmaf(cb[4], w1r4.y, h1);
    h2 = fmaf(cb[4], w1r4.z, h2); h3 = fmaf(cb[4], w1r4.w, h3);
    h0 = fmaf(cb[5], w1r5.x, h0); h1 = fmaf(cb[5], w1r5.y, h1);
    h2 = fmaf(cb[5], w1r5.z, h2); h3 = fmaf(cb[5], w1r5.w, h3);
    h0 = fmaxf(h0, 0.f); h1 = fmaxf(h1, 0.f);
    h2 = fmaxf(h2, 0.f); h3 = fmaxf(h3, 0.f);

    // LayerNorm over 256 channels (wave reduce)
    float s = h0 + h1 + h2 + h3;
    float s2 = h0 * h0 + h1 * h1 + h2 * h2 + h3 * h3;
    #pragma unroll
    for (int o = 32; o; o >>= 1) {
        s += __shfl_xor(s, o);
        s2 += __shfl_xor(s2, o);
    }
    const float mu = s * (1.0f / 256.0f);
    const float var = s2 * (1.0f / 256.0f) - mu * mu;
    const float inv = rsqrtf(var + 1e-5f);
    const float y0 = (h0 - mu) * inv * g.x + be.x;
    const float y1 = (h1 - mu) * inv * g.y + be.y;
    const float y2 = (h2 - mu) * inv * g.z + be.z;
    const float y3 = (h3 - mu) * inv * g.w + be.w;

    ushort4 hv, lv;
    hv.x = f2bf(y0); lv.x = f2bf(y0 - bf2f(hv.x));
    hv.y = f2bf(y1); lv.y = f2bf(y1 - bf2f(hv.y));
    hv.z = f2bf(y2); lv.z = f2bf(y2 - bf2f(hv.z));
    hv.w = f2bf(y3); lv.w = f2bf(y3 - bf2f(hv.w));

    // swizzled LDS write: e0 = lane*4 -> kt = lane>>3, q = (lane>>1)&3,
    // elem = (lane&1)*4
    const int pr = lr >> 1;
    const int phys = ((((lr & 1) << 2) | ((lane >> 1) & 3)) ^ (pr & 7));
    const int base = (lane >> 3) * 2048 + pr * 64 + phys * 8 + (lane & 1) * 4;
    *(ushort4*)(A_lds + base) = hv;
    *(ushort4*)(A_lds + base + 1024) = lv;
}

#define MFMA(acc, a, b) \
    (acc) = __builtin_amdgcn_mfma_f32_32x32x16_bf16((a), (b), (acc), 0, 0, 0)

__global__ __launch_bounds__(256, 4) void fused_kernel(
    const float* __restrict__ vel, const float* __restrict__ dist,
    const float* __restrict__ W1, const float* __restrict__ b1,
    const float* __restrict__ gammav, const float* __restrict__ betav,
    const unsigned short* __restrict__ bt_hi, const unsigned short* __restrict__ bt_lo,
    const float* __restrict__ b2, float* __restrict__ out)
{
    __shared__ __align__(16) unsigned short A_lds[16384];   // 32 KiB

    const int tid = threadIdx.x;
    const int lane = tid & 63;
    const int wid = tid >> 6;        // 0..3
    const int l31 = lane & 31;
    const int lh = lane >> 5;
    const int rowB = blockIdx.x * 32;

    // ---------------- phase 1: 8 rows per wave ----------------
    {
        const int e0 = lane * 4;
        const float4 w1r0 = *(const float4*)(W1 + 0 * 256 + e0);
        const float4 w1r1 = *(const float4*)(W1 + 1 * 256 + e0);
        const float4 w1r2 = *(const float4*)(W1 + 2 * 256 + e0);
        const float4 w1r3 = *(const float4*)(W1 + 3 * 256 + e0);
        const float4 w1r4 = *(const float4*)(W1 + 4 * 256 + e0);
        const float4 w1r5 = *(const float4*)(W1 + 5 * 256 + e0);
        const float4 bb = *(const float4*)(b1 + e0);
        const float4 g  = *(const float4*)(gammav + e0);
        const float4 be = *(const float4*)(betav + e0);

        int r = rowB + wid * 8;
        const float* dp = dist + (size_t)r * 1024 + lane * 4;
        float4 c0 = *(const float4*)(dp);
        float4 c1 = *(const float4*)(dp + 256);
        float4 c2 = *(const float4*)(dp + 512);
        float4 c3 = *(const float4*)(dp + 768);
        #pragma unroll
        for (int i = 0; i < 8; ++i) {
            float4 n0, n1, n2, n3;
            if (i < 7) {   // prefetch next row while current row computes
                const float* dn = dist + (size_t)(r + 1) * 1024 + lane * 4;
                n0 = *(const float4*)(dn);
                n1 = *(const float4*)(dn + 256);
                n2 = *(const float4*)(dn + 512);
                n3 = *(const float4*)(dn + 768);
            }
            process_row(c0, c1, c2, c3, r, wid * 8 + i, lane, vel,
                        w1r0, w1r1, w1r2, w1r3, w1r4, w1r5, bb, g, be, A_lds);
            c0 = n0; c1 = n1; c2 = n2; c3 = n3;
            ++r;
        }
    }
    __syncthreads();

    // ---------------- phase 2: barrier-free GEMM ----------------
    const int wn = wid;              // 0..3 (N 64-col group)

    f32x16 acc0, acc1;
    #pragma unroll
    for (int i = 0; i < 16; ++i) { acc0[i] = 0.f; acc1[i] = 0.f; }

    // A fragment address pieces: row = l31
    const int arow = l31;
    const int aB = (arow >> 1) * 64;
    const int aK = ((arow & 1) << 2) ^ ((arow >> 1) & 7);
    // B fragment: cols n0 = wn*64 + l31, n1 = n0 + 32
    const int n0 = wn * 64 + l31;
    const unsigned short* bh0 = bt_hi + n0 * 32;
    const unsigned short* bl0 = bt_lo + n0 * 32;
    const unsigned short* bh1 = bh0 + 32 * 32;
    const unsigned short* bl1 = bl0 + 32 * 32;

    #define LDS_F(off) __builtin_bit_cast(bf16x8, *(const u16x8*)(A_lds + (off)))
    #define GLB_F(p)   __builtin_bit_cast(bf16x8, *(const u16x8*)(p))

    #pragma unroll
    for (int kt = 0; kt < 8; ++kt) {
        #pragma unroll
        for (int ks = 0; ks < 2; ++ks) {
            const int q = ks * 2 + lh;
            const int aoff = kt * 2048 + aB + ((aK ^ q) << 3);
            const int boff = kt * 8192 + q * 8;
            bf16x8 ah = LDS_F(aoff);
            bf16x8 al = LDS_F(aoff + 1024);
            bf16x8 b0h = GLB_F(bh0 + boff);
            bf16x8 b0l = GLB_F(bl0 + boff);
            bf16x8 b1h = GLB_F(bh1 + boff);
            bf16x8 b1l = GLB_F(bl1 + boff);
            MFMA(acc0, ah, b0h); MFMA(acc0, ah, b0l); MFMA(acc0, al, b0h);
            MFMA(acc1, ah, b1h); MFMA(acc1, ah, b1l); MFMA(acc1, al, b1h);
        }
    }

    // epilogue: C/D layout col = lane&31, row = (reg&3) + 8*(reg>>2) + 4*lh
    const int col0 = wn * 64 + l31;
    const int col1 = col0 + 32;
    const float bias0 = b2[col0];
    const float bias1 = b2[col1];
    #pragma unroll
    for (int q2 = 0; q2 < 4; ++q2) {
        #pragma unroll
        for (int j = 0; j < 4; ++j) {
            const int reg = q2 * 4 + j;
            const size_t rg = (size_t)(rowB + j + 8 * q2 + 4 * lh);
            out[rg * 256 + col0] = acc0[reg] + bias0;
            out[rg * 256 + col1] = acc1[reg] + bias1;
        }
    }
}

// ---------------------------------------------------------------------------
extern "C" void kernel_launch(void* const* d_in, const int* in_sizes, int n_in,
                              void* d_out, int out_size, void* d_ws, size_t ws_size,
                              hipStream_t stream)
{
    const float* vel   = (const float*)d_in[0];
    const float* dist  = (const float*)d_in[1];
    const float* W1    = (const float*)d_in[2];
    const float* b1    = (const float*)d_in[3];
    const float* gam   = (const float*)d_in[4];
    const float* bet   = (const float*)d_in[5];
    const float* W2    = (const float*)d_in[6];
    const float* b2    = (const float*)d_in[7];
    float* out = (float*)d_out;

    unsigned short* bt_hi = (unsigned short*)d_ws;       // 256x256
    unsigned short* bt_lo = bt_hi + 65536ull;

    w2split_kernel<<<256, 256, 0, stream>>>(W2, bt_hi, bt_lo);
    fused_kernel<<<2048, 256, 0, stream>>>(vel, dist, W1, b1, gam, bet,
                                           bt_hi, bt_lo, b2, out);
}

// Round 5
// 418.875 us; speedup vs baseline: 1.0422x; 1.0422x over previous
//
#include <hip/hip_runtime.h>

// ---------------------------------------------------------------------------
// VelocityEncoder fully-fused pipeline for MI355X (gfx950)  — round 4 resubmit
//   (round-4 bench never ran: GPU acquisition timeout)
//   Changes vs round 3:
//   * phase-1 top-4 via threshold screening:
//       T = 4th-smallest of 64 per-lane minima (f32 only),
//       ballot-compaction of all values <= T into per-wave LDS (exact u64
//       keys as positive f64), 6-level bitonic top-4 merge on singles.
//       Slow path (cnt>64, ~never) = round-3 exact per-lane sort (f64 CE).
//   * keys as f64: v_min_f64/v_max_f64 = 2-instr 64-bit compare-exchange
//     (valid: keys are positive finite doubles, unique by index)
//   * amdgpu_waves_per_eu(4,4): force 128-VGPR budget, kill prefetch spills
// ---------------------------------------------------------------------------

typedef __bf16 bf16x8 __attribute__((ext_vector_type(8)));
typedef unsigned short u16x8 __attribute__((ext_vector_type(8)));
typedef float f32x16 __attribute__((ext_vector_type(16)));

static __device__ __forceinline__ unsigned short f2bf(float x) {
    unsigned u = __float_as_uint(x);
    u += 0x7FFFu + ((u >> 16) & 1u);   // round-to-nearest-even
    return (unsigned short)(u >> 16);
}
static __device__ __forceinline__ float bf2f(unsigned short u) {
    return __uint_as_float(((unsigned)u) << 16);
}

// f64 compare-exchange / min on (valbits<<32 | idx) keys stored as double.
// Keys are positive finite doubles (valbits of a non-negative finite f32 has
// bit31=0), unique by idx -> f64 total order == u64 key order.
#define CED(x, y) do { double _a = fmin((x), (y)), _b = fmax((x), (y)); \
                       (x) = _a; (y) = _b; } while (0)
#define CEF(x, y) do { float _a = fminf((x), (y)), _b = fmaxf((x), (y)); \
                       (x) = _a; (y) = _b; } while (0)

#define KEYD(val, idx) \
    __hiloint2double((int)__float_as_uint(val), (int)(idx))

#define PADD __hiloint2double(0x7FE00000, 0)   // > any key, finite

// ---------------------------------------------------------------------------
// W2 split: fp32 [k][n] -> bf16 hi/lo, layout [kt=k>>5][n][k&31]
// ---------------------------------------------------------------------------
__global__ __launch_bounds__(256) void w2split_kernel(
    const float* __restrict__ W2,
    unsigned short* __restrict__ bt_hi, unsigned short* __restrict__ bt_lo)
{
    const int k = blockIdx.x;    // 0..255
    const int n = threadIdx.x;   // 0..255
    const float w = W2[k * 256 + n];
    const unsigned short hi = f2bf(w);
    const unsigned short lo = f2bf(w - bf2f(hi));
    const size_t off = (size_t)(k >> 5) * 8192 + (size_t)n * 32 + (k & 31);
    bt_hi[off] = hi;
    bt_lo[off] = lo;
}

// ---------------------------------------------------------------------------
// LDS A-tile layout (ushort units), total 16384 ushorts = 32 KiB:
//   addr = kt*2048 + plane*1024 + (row>>1)*64 + phys*8 + elem
//   phys = (((row&1)<<2) | q) ^ ((row>>1)&7),  q = (k&31)>>3, elem = k&7
// ---------------------------------------------------------------------------

static __device__ __forceinline__ void process_row(
    float4 c0, float4 c1, float4 c2, float4 c3,
    int r, int lr, int lane,
    const float* __restrict__ vel,
    const float4 w1r0, const float4 w1r1, const float4 w1r2,
    const float4 w1r3, const float4 w1r4, const float4 w1r5,
    const float4 bb, const float4 g, const float4 be,
    unsigned short* __restrict__ A_lds, double* __restrict__ srow)
{
    const int ib = lane * 4;
    float v[16] = {c0.x, c0.y, c0.z, c0.w, c1.x, c1.y, c1.z, c1.w,
                   c2.x, c2.y, c2.z, c2.w, c3.x, c3.y, c3.z, c3.w};

    // ---- threshold T = 4th smallest of the 64 per-lane minima (f32) ----
    float m01 = fminf(fminf(v[0], v[1]), fminf(v[2], v[3]));
    float m23 = fminf(fminf(v[4], v[5]), fminf(v[6], v[7]));
    float m45 = fminf(fminf(v[8], v[9]), fminf(v[10], v[11]));
    float m67 = fminf(fminf(v[12], v[13]), fminf(v[14], v[15]));
    float m = fminf(fminf(m01, m23), fminf(m45, m67));

    float t0 = m, t1 = __int_as_float(0x7F800000),
          t2 = t1, t3 = t1;   // {m, inf, inf, inf}
    #pragma unroll
    for (int s = 1; s < 64; s <<= 1) {
        float p0 = __shfl_xor(t0, s);
        float p1 = __shfl_xor(t1, s);
        float p2 = __shfl_xor(t2, s);
        float p3 = __shfl_xor(t3, s);
        float l0 = fminf(t0, p3);
        float l1 = fminf(t1, p2);
        float l2 = fminf(t2, p1);
        float l3 = fminf(t3, p0);
        CEF(l0, l2); CEF(l1, l3); CEF(l0, l1); CEF(l2, l3);
        t0 = l0; t1 = l1; t2 = l2; t3 = l3;
    }
    const float T = t3;

    // ---- ballot-compact all survivors (v <= T) into LDS with exact keys ----
    int cnt = 0;
    #pragma unroll
    for (int k = 0; k < 16; ++k) {
        const bool p = v[k] <= T;
        const unsigned long long mask = __ballot(p);
        if (p) {
            const int rank = cnt + __builtin_amdgcn_mbcnt_hi(
                (unsigned)(mask >> 32),
                __builtin_amdgcn_mbcnt_lo((unsigned)mask, 0));
            if (rank < 64) {
                const int idx = (k >> 2) * 256 + ib + (k & 3);
                srow[rank] = KEYD(v[k], idx);
            }
        }
        cnt += (int)__popcll(mask);
    }
    __threadfence_block();

    double r0, r1, r2, r3;
    if (cnt <= 64) {
        // fast path: top-4 of <=64 single keys (>=4 survivors guaranteed)
        const int j = lane < cnt ? lane : 0;
        double x = srow[j];
        x = (lane < cnt) ? x : PADD;
        r0 = x; r1 = PADD; r2 = PADD; r3 = PADD;
    } else {
        // slow path (pathological ties): exact per-lane sorted top-4
        r0 = KEYD(v[0], ib + 0); r1 = KEYD(v[1], ib + 1);
        r2 = KEYD(v[2], ib + 2); r3 = KEYD(v[3], ib + 3);
        CED(r0, r2); CED(r1, r3); CED(r0, r1); CED(r2, r3); CED(r1, r2);
        #pragma unroll
        for (int j = 1; j < 4; ++j) {
            const int gb = j * 256 + ib;
            double g0 = KEYD(v[j * 4 + 0], gb + 0);
            double g1 = KEYD(v[j * 4 + 1], gb + 1);
            double g2 = KEYD(v[j * 4 + 2], gb + 2);
            double g3 = KEYD(v[j * 4 + 3], gb + 3);
            CED(g0, g2); CED(g1, g3); CED(g0, g1); CED(g2, g3); CED(g1, g2);
            double l0 = fmin(r0, g3);
            double l1 = fmin(r1, g2);
            double l2 = fmin(r2, g1);
            double l3 = fmin(r3, g0);
            CED(l0, l2); CED(l1, l3); CED(l0, l1); CED(l2, l3);
            r0 = l0; r1 = l1; r2 = l2; r3 = l3;
        }
    }

    // ---- 6-level bitonic top-4 allreduce across 64 lanes (f64 keys) ----
    #pragma unroll
    for (int s = 1; s < 64; s <<= 1) {
        double p0 = __shfl_xor(r0, s);
        double p1 = __shfl_xor(r1, s);
        double p2 = __shfl_xor(r2, s);
        double p3 = __shfl_xor(r3, s);
        double l0 = fmin(r0, p3);
        double l1 = fmin(r1, p2);
        double l2 = fmin(r2, p1);
        double l3 = fmin(r3, p0);
        CED(l0, l2); CED(l1, l3); CED(l0, l1); CED(l2, l3);
        r0 = l0; r1 = l1; r2 = l2; r3 = l3;
    }
    // neighbors = 2nd..4th smallest (reference drops idx[...,0])
    const unsigned i1 = (unsigned)__double2loint(r1);
    const unsigned i2 = (unsigned)__double2loint(r2);
    const unsigned i3 = (unsigned)__double2loint(r3);

    const float* va = vel + (size_t)r * 3;
    const size_t vb = (size_t)((r >> 10) << 10) * 3;
    const float* n1 = vel + vb + (size_t)i1 * 3;
    const float* n2 = vel + vb + (size_t)i2 * 3;
    const float* n3 = vel + vb + (size_t)i3 * 3;
    const float ax = va[0], ay = va[1], az = va[2];
    const float mx = (n1[0] + n2[0] + n3[0]) * (1.0f / 3.0f);
    const float my = (n1[1] + n2[1] + n3[1]) * (1.0f / 3.0f);
    const float mz = (n1[2] + n2[2] + n3[2]) * (1.0f / 3.0f);
    const float cb[6] = {ax, ay, az, ax - mx, ay - my, az - mz};

    // h[e] for e = lane*4 .. lane*4+3
    float h0 = bb.x, h1 = bb.y, h2 = bb.z, h3 = bb.w;
    h0 = fmaf(cb[0], w1r0.x, h0); h1 = fmaf(cb[0], w1r0.y, h1);
    h2 = fmaf(cb[0], w1r0.z, h2); h3 = fmaf(cb[0], w1r0.w, h3);
    h0 = fmaf(cb[1], w1r1.x, h0); h1 = fmaf(cb[1], w1r1.y, h1);
    h2 = fmaf(cb[1], w1r1.z, h2); h3 = fmaf(cb[1], w1r1.w, h3);
    h0 = fmaf(cb[2], w1r2.x, h0); h1 = fmaf(cb[2], w1r2.y, h1);
    h2 = fmaf(cb[2], w1r2.z, h2); h3 = fmaf(cb[2], w1r2.w, h3);
    h0 = fmaf(cb[3], w1r3.x, h0); h1 = fmaf(cb[3], w1r3.y, h1);
    h2 = fmaf(cb[3], w1r3.z, h2); h3 = fmaf(cb[3], w1r3.w, h3);
    h0 = fmaf(cb[4], w1r4.x, h0); h1 = fmaf(cb[4], w1r4.y, h1);
    h2 = fmaf(cb[4], w1r4.z, h2); h3 = fmaf(cb[4], w1r4.w, h3);
    h0 = fmaf(cb[5], w1r5.x, h0); h1 = fmaf(cb[5], w1r5.y, h1);
    h2 = fmaf(cb[5], w1r5.z, h2); h3 = fmaf(cb[5], w1r5.w, h3);
    h0 = fmaxf(h0, 0.f); h1 = fmaxf(h1, 0.f);
    h2 = fmaxf(h2, 0.f); h3 = fmaxf(h3, 0.f);

    // LayerNorm over 256 channels (wave reduce)
    float s = h0 + h1 + h2 + h3;
    float s2 = h0 * h0 + h1 * h1 + h2 * h2 + h3 * h3;
    #pragma unroll
    for (int o = 32; o; o >>= 1) {
        s += __shfl_xor(s, o);
        s2 += __shfl_xor(s2, o);
    }
    const float mu = s * (1.0f / 256.0f);
    const float var = s2 * (1.0f / 256.0f) - mu * mu;
    const float inv = rsqrtf(var + 1e-5f);
    const float y0 = (h0 - mu) * inv * g.x + be.x;
    const float y1 = (h1 - mu) * inv * g.y + be.y;
    const float y2 = (h2 - mu) * inv * g.z + be.z;
    const float y3 = (h3 - mu) * inv * g.w + be.w;

    ushort4 hv, lv;
    hv.x = f2bf(y0); lv.x = f2bf(y0 - bf2f(hv.x));
    hv.y = f2bf(y1); lv.y = f2bf(y1 - bf2f(hv.y));
    hv.z = f2bf(y2); lv.z = f2bf(y2 - bf2f(hv.z));
    hv.w = f2bf(y3); lv.w = f2bf(y3 - bf2f(hv.w));

    // swizzled LDS write: e0 = lane*4 -> kt = lane>>3, q = (lane>>1)&3,
    // elem = (lane&1)*4
    const int pr = lr >> 1;
    const int phys = ((((lr & 1) << 2) | ((lane >> 1) & 3)) ^ (pr & 7));
    const int base = (lane >> 3) * 2048 + pr * 64 + phys * 8 + (lane & 1) * 4;
    *(ushort4*)(A_lds + base) = hv;
    *(ushort4*)(A_lds + base + 1024) = lv;
}

#define MFMA(acc, a, b) \
    (acc) = __builtin_amdgcn_mfma_f32_32x32x16_bf16((a), (b), (acc), 0, 0, 0)

__global__ __launch_bounds__(256)
__attribute__((amdgpu_waves_per_eu(4, 4)))
void fused_kernel(
    const float* __restrict__ vel, const float* __restrict__ dist,
    const float* __restrict__ W1, const float* __restrict__ b1,
    const float* __restrict__ gammav, const float* __restrict__ betav,
    const unsigned short* __restrict__ bt_hi, const unsigned short* __restrict__ bt_lo,
    const float* __restrict__ b2, float* __restrict__ out)
{
    __shared__ __align__(16) unsigned short A_lds[16384];   // 32 KiB
    __shared__ __align__(16) double surv[4][64];            // 2 KiB

    const int tid = threadIdx.x;
    const int lane = tid & 63;
    const int wid = tid >> 6;        // 0..3
    const int l31 = lane & 31;
    const int lh = lane >> 5;
    const int rowB = blockIdx.x * 32;

    // ---------------- phase 1: 8 rows per wave ----------------
    {
        const int e0 = lane * 4;
        const float4 w1r0 = *(const float4*)(W1 + 0 * 256 + e0);
        const float4 w1r1 = *(const float4*)(W1 + 1 * 256 + e0);
        const float4 w1r2 = *(const float4*)(W1 + 2 * 256 + e0);
        const float4 w1r3 = *(const float4*)(W1 + 3 * 256 + e0);
        const float4 w1r4 = *(const float4*)(W1 + 4 * 256 + e0);
        const float4 w1r5 = *(const float4*)(W1 + 5 * 256 + e0);
        const float4 bb = *(const float4*)(b1 + e0);
        const float4 g  = *(const float4*)(gammav + e0);
        const float4 be = *(const float4*)(betav + e0);
        double* srow = &surv[wid][0];

        int r = rowB + wid * 8;
        const float* dp = dist + (size_t)r * 1024 + lane * 4;
        float4 c0 = *(const float4*)(dp);
        float4 c1 = *(const float4*)(dp + 256);
        float4 c2 = *(const float4*)(dp + 512);
        float4 c3 = *(const float4*)(dp + 768);
        #pragma unroll
        for (int i = 0; i < 8; ++i) {
            float4 n0, n1, n2, n3;
            if (i < 7) {   // prefetch next row while current row computes
                const float* dn = dist + (size_t)(r + 1) * 1024 + lane * 4;
                n0 = *(const float4*)(dn);
                n1 = *(const float4*)(dn + 256);
                n2 = *(const float4*)(dn + 512);
                n3 = *(const float4*)(dn + 768);
            }
            process_row(c0, c1, c2, c3, r, wid * 8 + i, lane, vel,
                        w1r0, w1r1, w1r2, w1r3, w1r4, w1r5, bb, g, be,
                        A_lds, srow);
            c0 = n0; c1 = n1; c2 = n2; c3 = n3;
            ++r;
        }
    }
    __syncthreads();

    // ---------------- phase 2: barrier-free GEMM ----------------
    const int wn = wid;              // 0..3 (N 64-col group)

    f32x16 acc0, acc1;
    #pragma unroll
    for (int i = 0; i < 16; ++i) { acc0[i] = 0.f; acc1[i] = 0.f; }

    // A fragment address pieces: row = l31
    const int arow = l31;
    const int aB = (arow >> 1) * 64;
    const int aK = ((arow & 1) << 2) ^ ((arow >> 1) & 7);
    // B fragment: cols n0 = wn*64 + l31, n1 = n0 + 32
    const int n0 = wn * 64 + l31;
    const unsigned short* bh0 = bt_hi + n0 * 32;
    const unsigned short* bl0 = bt_lo + n0 * 32;
    const unsigned short* bh1 = bh0 + 32 * 32;
    const unsigned short* bl1 = bl0 + 32 * 32;

    #define LDS_F(off) __builtin_bit_cast(bf16x8, *(const u16x8*)(A_lds + (off)))
    #define GLB_F(p)   __builtin_bit_cast(bf16x8, *(const u16x8*)(p))

    #pragma unroll
    for (int kt = 0; kt < 8; ++kt) {
        #pragma unroll
        for (int ks = 0; ks < 2; ++ks) {
            const int q = ks * 2 + lh;
            const int aoff = kt * 2048 + aB + ((aK ^ q) << 3);
            const int boff = kt * 8192 + q * 8;
            bf16x8 ah = LDS_F(aoff);
            bf16x8 al = LDS_F(aoff + 1024);
            bf16x8 b0h = GLB_F(bh0 + boff);
            bf16x8 b0l = GLB_F(bl0 + boff);
            bf16x8 b1h = GLB_F(bh1 + boff);
            bf16x8 b1l = GLB_F(bl1 + boff);
            MFMA(acc0, ah, b0h); MFMA(acc0, ah, b0l); MFMA(acc0, al, b0h);
            MFMA(acc1, ah, b1h); MFMA(acc1, ah, b1l); MFMA(acc1, al, b1h);
        }
    }

    // epilogue: C/D layout col = lane&31, row = (reg&3) + 8*(reg>>2) + 4*lh
    const int col0 = wn * 64 + l31;
    const int col1 = col0 + 32;
    const float bias0 = b2[col0];
    const float bias1 = b2[col1];
    #pragma unroll
    for (int q2 = 0; q2 < 4; ++q2) {
        #pragma unroll
        for (int j = 0; j < 4; ++j) {
            const int reg = q2 * 4 + j;
            const size_t rg = (size_t)(rowB + j + 8 * q2 + 4 * lh);
            out[rg * 256 + col0] = acc0[reg] + bias0;
            out[rg * 256 + col1] = acc1[reg] + bias1;
        }
    }
}

// ---------------------------------------------------------------------------
extern "C" void kernel_launch(void* const* d_in, const int* in_sizes, int n_in,
                              void* d_out, int out_size, void* d_ws, size_t ws_size,
                              hipStream_t stream)
{
    const float* vel   = (const float*)d_in[0];
    const float* dist  = (const float*)d_in[1];
    const float* W1    = (const float*)d_in[2];
    const float* b1    = (const float*)d_in[3];
    const float* gam   = (const float*)d_in[4];
    const float* bet   = (const float*)d_in[5];
    const float* W2    = (const float*)d_in[6];
    const float* b2    = (const float*)d_in[7];
    float* out = (float*)d_out;

    unsigned short* bt_hi = (unsigned short*)d_ws;       // 256x256
    unsigned short* bt_lo = bt_hi + 65536ull;

    w2split_kernel<<<256, 256, 0, stream>>>(W2, bt_hi, bt_lo);
    fused_kernel<<<2048, 256, 0, stream>>>(vel, dist, W1, b1, gam, bet,
                                           bt_hi, bt_lo, b2, out);
}